// Round 2
// baseline (11569.387 us; speedup 1.0000x reference)
//
#include <hip/hip_runtime.h>

#define DT_C 0.1f

__device__ __forceinline__ float sigm(float z)  { return 1.0f / (1.0f + __expf(-z)); }
__device__ __forceinline__ float tanhf_(float z){ return 2.0f / (1.0f + __expf(-2.0f * z)) - 1.0f; }

// Butterfly sum over aligned 8-lane groups, entirely on the VALU via DPP.
// Masks {1,2,7} span Z2^3: quad_perm xor1 (0xB1), quad_perm xor2 (0x4E),
// row_half_mirror = xor7 (0x141). No DS-pipe traffic.
__device__ __forceinline__ float red8(float v) {
    v += __int_as_float(__builtin_amdgcn_update_dpp(0, __float_as_int(v), 0xB1,  0xF, 0xF, true));
    v += __int_as_float(__builtin_amdgcn_update_dpp(0, __float_as_int(v), 0x4E,  0xF, 0xF, true));
    v += __int_as_float(__builtin_amdgcn_update_dpp(0, __float_as_int(v), 0x141, 0xF, 0xF, true));
    return v;
}

// B=256, S=2048, I=1, H=128, O=1
// Grid: 256 blocks (one per batch row). Block: 512 threads, t = jg*8 + ks.
// Thread (jg,ks) computes output rows j0=jg and j1=jg+64, k-slice
// [ks*16, ks*16+16) of W_att/W_rec/W_acc held in VGPRs (96 floats).
// k-partials reduced across the 8 ks lanes via DPP butterfly.
// LDS float4 reads de-rotated by (ks>>1) so the 8 distinct 16B addresses
// per instruction tile all 32 banks (conflict-free).
__global__ __launch_bounds__(512, 2)
void clnm_kernel(const float* __restrict__ x,      // [256,2048]
                 const float* __restrict__ W_in,   // [128,1]
                 const float* __restrict__ b_in,   // [128]
                 const float* __restrict__ W_rec,  // [128,128]
                 const float* __restrict__ b_rec,  // [128]
                 const float* __restrict__ tau,    // [128]
                 const float* __restrict__ W_att,  // [128,128]
                 const float* __restrict__ b_att,  // [128]
                 const float* __restrict__ W_ev,   // [1,2]
                 const float* __restrict__ b_ev,   // [1]
                 const float* __restrict__ W_acc,  // [128,128]
                 const float* __restrict__ b_acc,  // [128]
                 const float* __restrict__ W_out,  // [1,128]
                 const float* __restrict__ b_out,  // [1]
                 float* __restrict__ out,          // [256]
                 float* __restrict__ out_ew)       // [256,2048]
{
    const int t   = threadIdx.x;
    const int jg  = t >> 3;        // 0..63
    const int ks  = t & 7;         // 0..7
    const int j0  = jg;
    const int j1  = jg + 64;
    const int r   = blockIdx.x;
    const int rot = ks >> 1;       // bank de-rotation for float4 LDS reads

    __shared__ __align__(16) float x_lds[2048];
    __shared__ __align__(16) float h_lds[128];
    __shared__ __align__(16) float hatt_lds[128];
    __shared__ float red_s[8];

    // Stage this row's x into LDS (coalesced float4).
    ((float4*)x_lds)[t] = ((const float4*)(x + (size_t)r * 2048))[t];

    // Persistent weight slices in registers: wX[g][kk] = W[row_g][ks*16+kk].
    float wA[2][16], wR[2][16], wC[2][16];
    {
        const float4* a4 = (const float4*)W_att;
        const float4* r4 = (const float4*)W_rec;
        const float4* c4 = (const float4*)W_acc;
#pragma unroll
        for (int g = 0; g < 2; ++g) {
            const int base = (g ? j1 : j0) * 32 + ks * 4;   // float4 index
#pragma unroll
            for (int i = 0; i < 4; ++i) {
                float4 v;
                v = a4[base + i]; wA[g][4*i]=v.x; wA[g][4*i+1]=v.y; wA[g][4*i+2]=v.z; wA[g][4*i+3]=v.w;
                v = r4[base + i]; wR[g][4*i]=v.x; wR[g][4*i+1]=v.y; wR[g][4*i+2]=v.z; wR[g][4*i+3]=v.w;
                v = c4[base + i]; wC[g][4*i]=v.x; wC[g][4*i+1]=v.y; wC[g][4*i+2]=v.z; wC[g][4*i+3]=v.w;
            }
        }
    }

    const float w_in0 = W_in[j0],  w_in1 = W_in[j1];
    const float b_in0 = b_in[j0],  b_in1 = b_in[j1];
    const float bA0   = b_att[j0], bA1   = b_att[j1];
    const float bR0   = b_rec[j0], bR1   = b_rec[j1];
    const float bC0   = b_acc[j0], bC1   = b_acc[j1];
    const float wo0   = W_out[j0], wo1   = W_out[j1];
    const float ti0   = 1.0f / fminf(fmaxf(tau[j0], 0.1f), 10.0f);
    const float ti1   = 1.0f / fminf(fmaxf(tau[j1], 0.1f), 10.0f);
    const float wev0 = W_ev[0], wev1 = W_ev[1], bev = b_ev[0], bout = b_out[0];

    if (t < 128) h_lds[t] = 0.0f;
    __syncthreads();

    const float4* h4  = ((const float4*)h_lds)    + ks * 4;  // this thread's k-slice
    const float4* ha4 = ((const float4*)hatt_lds) + ks * 4;

    float hj0 = 0.0f, hj1 = 0.0f, ac0 = 0.0f, ac1 = 0.0f, xprev = 0.0f;

    // Register h-slice (h_t[ks*16..+16)); reused by ACC(t-1) and ATT(t).
    float4 hv[4];
#pragma unroll
    for (int i = 0; i < 4; ++i) hv[i] = make_float4(0.f, 0.f, 0.f, 0.f);

    for (int s = 0; s < 2048; ++s) {
        const float xt = x_lds[s];
        const float ew = (s == 0) ? 0.0f : sigm(fmaf(wev0, xt, fmaf(wev1, xprev, bev)));
        xprev = xt;
        if (t == 0) out_ew[(size_t)r * 2048 + s] = ew;
        const float ic0 = tanhf_(fmaf(xt, w_in0, b_in0));
        const float ic1 = tanhf_(fmaf(xt, w_in1, b_in1));

        // ---- ATT: att = sigmoid(h @ W_att^T + b_att) ----
        float sa0 = 0.f, sa1 = 0.f;
#pragma unroll
        for (int i = 0; i < 4; ++i) {
            const float* hp = (const float*)&hv[i];
#pragma unroll
            for (int e = 0; e < 4; ++e) {
                sa0 = fmaf(wA[0][4*i+e], hp[e], sa0);
                sa1 = fmaf(wA[1][4*i+e], hp[e], sa1);
            }
        }
        sa0 = red8(sa0); sa1 = red8(sa1);
        const float att0 = sigm(sa0 + bA0);
        const float att1 = sigm(sa1 + bA1);
        if (ks == 0) { hatt_lds[j0] = hj0 * att0; hatt_lds[j1] = hj1 * att1; }
        __syncthreads();   // A: hatt visible; all reads of h_t (regs) already done

        // ---- REC: rec = tanh((h*att) @ W_rec^T + b_rec) ----
        float4 av[4];
#pragma unroll
        for (int m = 0; m < 4; ++m) { const int ii = (m + rot) & 3; av[ii] = ha4[ii]; }
        float sr0 = 0.f, sr1 = 0.f;
#pragma unroll
        for (int i = 0; i < 4; ++i) {
            const float* ap = (const float*)&av[i];
#pragma unroll
            for (int e = 0; e < 4; ++e) {
                sr0 = fmaf(wR[0][4*i+e], ap[e], sr0);
                sr1 = fmaf(wR[1][4*i+e], ap[e], sr1);
            }
        }
        sr0 = red8(sr0); sr1 = red8(sr1);
        const float rec0 = tanhf_(sr0 + bR0);
        const float rec1 = tanhf_(sr1 + bR1);
        const float kk = DT_C * (1.0f + ew);
        hj0 = fmaf(kk * ti0, (ic0 + rec0) - hj0, hj0);
        hj1 = fmaf(kk * ti1, (ic1 + rec1) - hj1, hj1);
        if (ks == 0) { h_lds[j0] = hj0; h_lds[j1] = hj1; }
        __syncthreads();   // B: h_{t+1} visible

        // Reload register h-slice (h_{t+1}); used by ACC now and ATT next step.
#pragma unroll
        for (int m = 0; m < 4; ++m) { const int ii = (m + rot) & 3; hv[ii] = h4[ii]; }

        // ---- ACC: acc = 0.9 acc + 0.1 tanh(h_new @ W_acc^T + b_acc) * ew ----
        float sc0 = 0.f, sc1 = 0.f;
#pragma unroll
        for (int i = 0; i < 4; ++i) {
            const float* hp = (const float*)&hv[i];
#pragma unroll
            for (int e = 0; e < 4; ++e) {
                sc0 = fmaf(wC[0][4*i+e], hp[e], sc0);
                sc1 = fmaf(wC[1][4*i+e], hp[e], sc1);
            }
        }
        sc0 = red8(sc0); sc1 = red8(sc1);
        ac0 = fmaf(0.1f * ew, tanhf_(sc0 + bC0), 0.9f * ac0);
        ac1 = fmaf(0.1f * ew, tanhf_(sc1 + bC1), 0.9f * ac1);
    }

    // ---- Output: out[r] = sum_j (h_f[j] + acc_f[j]) * W_out[j] + b_out ----
    float val = (ks == 0) ? fmaf(hj0 + ac0, wo0, (hj1 + ac1) * wo1) : 0.0f;
#pragma unroll
    for (int m = 1; m < 64; m <<= 1) val += __shfl_xor(val, m);
    const int wave = t >> 6, lane = t & 63;
    if (lane == 0) red_s[wave] = val;
    __syncthreads();
    if (t == 0) {
        float o = bout;
#pragma unroll
        for (int w = 0; w < 8; ++w) o += red_s[w];
        out[r] = o;
    }
}

extern "C" void kernel_launch(void* const* d_in, const int* in_sizes, int n_in,
                              void* d_out, int out_size, void* d_ws, size_t ws_size,
                              hipStream_t stream) {
    const float* x     = (const float*)d_in[0];
    const float* W_in  = (const float*)d_in[1];
    const float* b_in  = (const float*)d_in[2];
    const float* W_rec = (const float*)d_in[3];
    const float* b_rec = (const float*)d_in[4];
    const float* tau   = (const float*)d_in[5];
    const float* W_att = (const float*)d_in[6];
    const float* b_att = (const float*)d_in[7];
    const float* W_ev  = (const float*)d_in[8];
    const float* b_ev  = (const float*)d_in[9];
    const float* W_acc = (const float*)d_in[10];
    const float* b_acc = (const float*)d_in[11];
    const float* W_out = (const float*)d_in[12];
    const float* b_out = (const float*)d_in[13];

    float* out    = (float*)d_out;        // [256,1]
    float* out_ew = out + 256;            // [256,2048]

    clnm_kernel<<<256, 512, 0, stream>>>(x, W_in, b_in, W_rec, b_rec, tau,
                                         W_att, b_att, W_ev, b_ev,
                                         W_acc, b_acc, W_out, b_out,
                                         out, out_ew);
}

// Round 3
// 2236.172 us; speedup vs baseline: 5.1737x; 5.1737x over previous
//
#include <hip/hip_runtime.h>

#define DT_C 0.1f

__device__ __forceinline__ float sigm(float z)  { return 1.0f / (1.0f + __expf(-z)); }
__device__ __forceinline__ float tanhf_(float z){ return 2.0f / (1.0f + __expf(-2.0f * z)) - 1.0f; }

// 8-lane butterfly sum on the VALU via DPP: xor1 (quad_perm 0xB1),
// xor2 (quad_perm 0x4E), xor7 (row_half_mirror 0x141). HW-verified R2.
__device__ __forceinline__ float red8(float v) {
    v += __int_as_float(__builtin_amdgcn_update_dpp(0, __float_as_int(v), 0xB1,  0xF, 0xF, true));
    v += __int_as_float(__builtin_amdgcn_update_dpp(0, __float_as_int(v), 0x4E,  0xF, 0xF, true));
    v += __int_as_float(__builtin_amdgcn_update_dpp(0, __float_as_int(v), 0x141, 0xF, 0xF, true));
    return v;
}

// B=256, S=2048, I=1, H=128, O=1.
// Grid: 256 blocks (1 per batch row, 1 per CU). Block: 512 threads, t=jg*8+ks.
// Thread (jg,ks): output rows j0=jg, j1=jg+64; k-slice [ks*16, ks*16+16).
// Weights for both rows of W_att/W_rec/W_acc in VGPRs (96 floats), loaded in
// ROTATED chunk order (rot=ks>>1) so the in-loop LDS float4 reads — issued at
// rotated addresses with compile-time register destinations — are
// bank-conflict-free (8 distinct chunks/instruction tile all 32 banks; the 8
// same-ks lanes broadcast). NO runtime-indexed register arrays (R2 lesson:
// they demote to scratch -> 11 GB of HBM spill traffic).
__global__ __launch_bounds__(512, 2)
void clnm_kernel(const float* __restrict__ x,      // [256,2048]
                 const float* __restrict__ W_in,   // [128,1]
                 const float* __restrict__ b_in,   // [128]
                 const float* __restrict__ W_rec,  // [128,128]
                 const float* __restrict__ b_rec,  // [128]
                 const float* __restrict__ tau,    // [128]
                 const float* __restrict__ W_att,  // [128,128]
                 const float* __restrict__ b_att,  // [128]
                 const float* __restrict__ W_ev,   // [1,2]
                 const float* __restrict__ b_ev,   // [1]
                 const float* __restrict__ W_acc,  // [128,128]
                 const float* __restrict__ b_acc,  // [128]
                 const float* __restrict__ W_out,  // [1,128]
                 const float* __restrict__ b_out,  // [1]
                 float* __restrict__ out,          // [256]
                 float* __restrict__ out_ew)       // [256,2048]
{
    const int t   = threadIdx.x;
    const int jg  = t >> 3;        // 0..63
    const int ks  = t & 7;         // 0..7
    const int j0  = jg;
    const int j1  = jg + 64;
    const int r   = blockIdx.x;
    const int rot = ks >> 1;

    __shared__ __align__(16) float  x_stage[2048];   // staging only
    __shared__ __align__(16) float2 xe_lds[2048];    // {x_t, ew_t}
    __shared__ __align__(16) float  h_lds[128];
    __shared__ __align__(16) float  hatt_lds[128];
    __shared__ float red_s[8];

    const float wev0 = W_ev[0], wev1 = W_ev[1], bev = b_ev[0], bout = b_out[0];

    // Stage x (coalesced float4).
    ((float4*)x_stage)[t] = ((const float4*)(x + (size_t)r * 2048))[t];
    if (t < 128) h_lds[t] = 0.0f;
    __syncthreads();

    // Precompute ew for 4 steps/thread; pack {x,ew} and store out_ew coalesced.
    {
        const int s0 = t * 4;
        const float x0 = x_stage[s0], x1 = x_stage[s0 + 1];
        const float x2 = x_stage[s0 + 2], x3 = x_stage[s0 + 3];
        const float xm1 = (t == 0) ? 0.0f : x_stage[s0 - 1];
        const float e0 = (s0 == 0) ? 0.0f : sigm(fmaf(wev0, x0, fmaf(wev1, xm1, bev)));
        const float e1 = sigm(fmaf(wev0, x1, fmaf(wev1, x0, bev)));
        const float e2 = sigm(fmaf(wev0, x2, fmaf(wev1, x1, bev)));
        const float e3 = sigm(fmaf(wev0, x3, fmaf(wev1, x2, bev)));
        ((float4*)xe_lds)[2 * t]     = make_float4(x0, e0, x1, e1);
        ((float4*)xe_lds)[2 * t + 1] = make_float4(x2, e2, x3, e3);
        ((float4*)(out_ew + (size_t)r * 2048))[t] = make_float4(e0, e1, e2, e3);
    }

    // Rotated chunk indices (loop-invariant). q_m = ks*4 + ((m+rot)&3).
    const int q0 = ks * 4 + ((0 + rot) & 3);
    const int q1 = ks * 4 + ((1 + rot) & 3);
    const int q2 = ks * 4 + ((2 + rot) & 3);
    const int q3 = ks * 4 + ((3 + rot) & 3);

    // Weights in registers, chunk m holds global float4 (row*32 + q_m).
    float4 wa[2][4], wr[2][4], wc[2][4];
    {
        const float4* a4 = (const float4*)W_att;
        const float4* r4 = (const float4*)W_rec;
        const float4* c4 = (const float4*)W_acc;
        const int b0 = j0 * 32, b1 = j1 * 32;
        wa[0][0] = a4[b0 + q0]; wa[0][1] = a4[b0 + q1]; wa[0][2] = a4[b0 + q2]; wa[0][3] = a4[b0 + q3];
        wa[1][0] = a4[b1 + q0]; wa[1][1] = a4[b1 + q1]; wa[1][2] = a4[b1 + q2]; wa[1][3] = a4[b1 + q3];
        wr[0][0] = r4[b0 + q0]; wr[0][1] = r4[b0 + q1]; wr[0][2] = r4[b0 + q2]; wr[0][3] = r4[b0 + q3];
        wr[1][0] = r4[b1 + q0]; wr[1][1] = r4[b1 + q1]; wr[1][2] = r4[b1 + q2]; wr[1][3] = r4[b1 + q3];
        wc[0][0] = c4[b0 + q0]; wc[0][1] = c4[b0 + q1]; wc[0][2] = c4[b0 + q2]; wc[0][3] = c4[b0 + q3];
        wc[1][0] = c4[b1 + q0]; wc[1][1] = c4[b1 + q1]; wc[1][2] = c4[b1 + q2]; wc[1][3] = c4[b1 + q3];
    }

    const float w_in0 = W_in[j0],  w_in1 = W_in[j1];
    const float b_in0 = b_in[j0],  b_in1 = b_in[j1];
    const float bA0   = b_att[j0], bA1   = b_att[j1];
    const float bR0   = b_rec[j0], bR1   = b_rec[j1];
    const float bC0   = b_acc[j0], bC1   = b_acc[j1];
    const float wo0   = W_out[j0], wo1   = W_out[j1];
    const float ti0   = 1.0f / fminf(fmaxf(tau[j0], 0.1f), 10.0f);
    const float ti1   = 1.0f / fminf(fmaxf(tau[j1], 0.1f), 10.0f);

    __syncthreads();   // h_lds zeros + xe_lds visible

    const float4* h4  = (const float4*)h_lds;
    const float4* ha4 = (const float4*)hatt_lds;

    float hj0 = 0.0f, hj1 = 0.0f, ac0 = 0.0f, ac1 = 0.0f;

    // h-slice cache (rotated chunk order, matches weight order). Starts 0.
    float4 hv0 = make_float4(0,0,0,0), hv1 = hv0, hv2 = hv0, hv3 = hv0;

    for (int s = 0; s < 2048; ++s) {
        const float2 xe = xe_lds[s];          // broadcast ds_read_b64
        const float xt = xe.x, ew = xe.y;
        const float ic0 = tanhf_(fmaf(xt, w_in0, b_in0));
        const float ic1 = tanhf_(fmaf(xt, w_in1, b_in1));

        // ---- ATT: sigmoid(h @ W_att^T + b) ---- (h from regs)
        float a0x = wa[0][0].x * hv0.x, a0y = wa[0][0].y * hv0.y;
        float a0z = wa[0][0].z * hv0.z, a0w = wa[0][0].w * hv0.w;
        float a1x = wa[1][0].x * hv0.x, a1y = wa[1][0].y * hv0.y;
        float a1z = wa[1][0].z * hv0.z, a1w = wa[1][0].w * hv0.w;
        a0x = fmaf(wa[0][1].x, hv1.x, a0x); a0y = fmaf(wa[0][1].y, hv1.y, a0y);
        a0z = fmaf(wa[0][1].z, hv1.z, a0z); a0w = fmaf(wa[0][1].w, hv1.w, a0w);
        a1x = fmaf(wa[1][1].x, hv1.x, a1x); a1y = fmaf(wa[1][1].y, hv1.y, a1y);
        a1z = fmaf(wa[1][1].z, hv1.z, a1z); a1w = fmaf(wa[1][1].w, hv1.w, a1w);
        a0x = fmaf(wa[0][2].x, hv2.x, a0x); a0y = fmaf(wa[0][2].y, hv2.y, a0y);
        a0z = fmaf(wa[0][2].z, hv2.z, a0z); a0w = fmaf(wa[0][2].w, hv2.w, a0w);
        a1x = fmaf(wa[1][2].x, hv2.x, a1x); a1y = fmaf(wa[1][2].y, hv2.y, a1y);
        a1z = fmaf(wa[1][2].z, hv2.z, a1z); a1w = fmaf(wa[1][2].w, hv2.w, a1w);
        a0x = fmaf(wa[0][3].x, hv3.x, a0x); a0y = fmaf(wa[0][3].y, hv3.y, a0y);
        a0z = fmaf(wa[0][3].z, hv3.z, a0z); a0w = fmaf(wa[0][3].w, hv3.w, a0w);
        a1x = fmaf(wa[1][3].x, hv3.x, a1x); a1y = fmaf(wa[1][3].y, hv3.y, a1y);
        a1z = fmaf(wa[1][3].z, hv3.z, a1z); a1w = fmaf(wa[1][3].w, hv3.w, a1w);
        const float att0 = sigm(red8((a0x + a0y) + (a0z + a0w)) + bA0);
        const float att1 = sigm(red8((a1x + a1y) + (a1z + a1w)) + bA1);
        if (ks == 0) { hatt_lds[j0] = hj0 * att0; hatt_lds[j1] = hj1 * att1; }
        __syncthreads();   // A: hatt visible

        // ---- REC: tanh((h*att) @ W_rec^T + b) ----
        const float4 av0 = ha4[q0], av1 = ha4[q1], av2 = ha4[q2], av3 = ha4[q3];
        float r0x = wr[0][0].x * av0.x, r0y = wr[0][0].y * av0.y;
        float r0z = wr[0][0].z * av0.z, r0w = wr[0][0].w * av0.w;
        float r1x = wr[1][0].x * av0.x, r1y = wr[1][0].y * av0.y;
        float r1z = wr[1][0].z * av0.z, r1w = wr[1][0].w * av0.w;
        r0x = fmaf(wr[0][1].x, av1.x, r0x); r0y = fmaf(wr[0][1].y, av1.y, r0y);
        r0z = fmaf(wr[0][1].z, av1.z, r0z); r0w = fmaf(wr[0][1].w, av1.w, r0w);
        r1x = fmaf(wr[1][1].x, av1.x, r1x); r1y = fmaf(wr[1][1].y, av1.y, r1y);
        r1z = fmaf(wr[1][1].z, av1.z, r1z); r1w = fmaf(wr[1][1].w, av1.w, r1w);
        r0x = fmaf(wr[0][2].x, av2.x, r0x); r0y = fmaf(wr[0][2].y, av2.y, r0y);
        r0z = fmaf(wr[0][2].z, av2.z, r0z); r0w = fmaf(wr[0][2].w, av2.w, r0w);
        r1x = fmaf(wr[1][2].x, av2.x, r1x); r1y = fmaf(wr[1][2].y, av2.y, r1y);
        r1z = fmaf(wr[1][2].z, av2.z, r1z); r1w = fmaf(wr[1][2].w, av2.w, r1w);
        r0x = fmaf(wr[0][3].x, av3.x, r0x); r0y = fmaf(wr[0][3].y, av3.y, r0y);
        r0z = fmaf(wr[0][3].z, av3.z, r0z); r0w = fmaf(wr[0][3].w, av3.w, r0w);
        r1x = fmaf(wr[1][3].x, av3.x, r1x); r1y = fmaf(wr[1][3].y, av3.y, r1y);
        r1z = fmaf(wr[1][3].z, av3.z, r1z); r1w = fmaf(wr[1][3].w, av3.w, r1w);
        const float rec0 = tanhf_(red8((r0x + r0y) + (r0z + r0w)) + bR0);
        const float rec1 = tanhf_(red8((r1x + r1y) + (r1z + r1w)) + bR1);
        const float kk = DT_C * (1.0f + ew);
        hj0 = fmaf(kk * ti0, (ic0 + rec0) - hj0, hj0);
        hj1 = fmaf(kk * ti1, (ic1 + rec1) - hj1, hj1);
        if (ks == 0) { h_lds[j0] = hj0; h_lds[j1] = hj1; }
        __syncthreads();   // B: h_{t+1} visible

        // Reload h-slice (used by ACC now and ATT next step).
        hv0 = h4[q0]; hv1 = h4[q1]; hv2 = h4[q2]; hv3 = h4[q3];

        // ---- ACC: 0.9*acc + 0.1*tanh(h_new @ W_acc^T + b)*ew ----
        float c0x = wc[0][0].x * hv0.x, c0y = wc[0][0].y * hv0.y;
        float c0z = wc[0][0].z * hv0.z, c0w = wc[0][0].w * hv0.w;
        float c1x = wc[1][0].x * hv0.x, c1y = wc[1][0].y * hv0.y;
        float c1z = wc[1][0].z * hv0.z, c1w = wc[1][0].w * hv0.w;
        c0x = fmaf(wc[0][1].x, hv1.x, c0x); c0y = fmaf(wc[0][1].y, hv1.y, c0y);
        c0z = fmaf(wc[0][1].z, hv1.z, c0z); c0w = fmaf(wc[0][1].w, hv1.w, c0w);
        c1x = fmaf(wc[1][1].x, hv1.x, c1x); c1y = fmaf(wc[1][1].y, hv1.y, c1y);
        c1z = fmaf(wc[1][1].z, hv1.z, c1z); c1w = fmaf(wc[1][1].w, hv1.w, c1w);
        c0x = fmaf(wc[0][2].x, hv2.x, c0x); c0y = fmaf(wc[0][2].y, hv2.y, c0y);
        c0z = fmaf(wc[0][2].z, hv2.z, c0z); c0w = fmaf(wc[0][2].w, hv2.w, c0w);
        c1x = fmaf(wc[1][2].x, hv2.x, c1x); c1y = fmaf(wc[1][2].y, hv2.y, c1y);
        c1z = fmaf(wc[1][2].z, hv2.z, c1z); c1w = fmaf(wc[1][2].w, hv2.w, c1w);
        c0x = fmaf(wc[0][3].x, hv3.x, c0x); c0y = fmaf(wc[0][3].y, hv3.y, c0y);
        c0z = fmaf(wc[0][3].z, hv3.z, c0z); c0w = fmaf(wc[0][3].w, hv3.w, c0w);
        c1x = fmaf(wc[1][3].x, hv3.x, c1x); c1y = fmaf(wc[1][3].y, hv3.y, c1y);
        c1z = fmaf(wc[1][3].z, hv3.z, c1z); c1w = fmaf(wc[1][3].w, hv3.w, c1w);
        const float t0 = tanhf_(red8((c0x + c0y) + (c0z + c0w)) + bC0);
        const float t1 = tanhf_(red8((c1x + c1y) + (c1z + c1w)) + bC1);
        const float ewp = 0.1f * ew;
        ac0 = fmaf(ewp, t0, 0.9f * ac0);
        ac1 = fmaf(ewp, t1, 0.9f * ac1);
    }

    // ---- Output: out[r] = sum_j (h_f + acc_f)[j] * W_out[j] + b_out ----
    float val = (ks == 0) ? fmaf(hj0 + ac0, wo0, (hj1 + ac1) * wo1) : 0.0f;
#pragma unroll
    for (int m = 1; m < 64; m <<= 1) val += __shfl_xor(val, m);
    const int wave = t >> 6, lane = t & 63;
    if (lane == 0) red_s[wave] = val;
    __syncthreads();
    if (t == 0) {
        float o = bout;
#pragma unroll
        for (int w = 0; w < 8; ++w) o += red_s[w];
        out[r] = o;
    }
}

extern "C" void kernel_launch(void* const* d_in, const int* in_sizes, int n_in,
                              void* d_out, int out_size, void* d_ws, size_t ws_size,
                              hipStream_t stream) {
    const float* x     = (const float*)d_in[0];
    const float* W_in  = (const float*)d_in[1];
    const float* b_in  = (const float*)d_in[2];
    const float* W_rec = (const float*)d_in[3];
    const float* b_rec = (const float*)d_in[4];
    const float* tau   = (const float*)d_in[5];
    const float* W_att = (const float*)d_in[6];
    const float* b_att = (const float*)d_in[7];
    const float* W_ev  = (const float*)d_in[8];
    const float* b_ev  = (const float*)d_in[9];
    const float* W_acc = (const float*)d_in[10];
    const float* b_acc = (const float*)d_in[11];
    const float* W_out = (const float*)d_in[12];
    const float* b_out = (const float*)d_in[13];

    float* out    = (float*)d_out;        // [256,1]
    float* out_ew = out + 256;            // [256,2048]

    clnm_kernel<<<256, 512, 0, stream>>>(x, W_in, b_in, W_rec, b_rec, tau,
                                         W_att, b_att, W_ev, b_ev,
                                         W_acc, b_acc, W_out, b_out,
                                         out, out_ew);
}